// Round 1
// baseline (8402.299 us; speedup 1.0000x reference)
//
#include <hip/hip_runtime.h>
#include <cstdint>
#include <cstddef>

#define N_NODES 100000
#define N_EDGES 1600000
#define IN_DIM 963
#define HID 192
#define OUT_DIM 3

// ---------------------------------------------------------------------------
// CSR build (deterministic: rows sorted by original edge index)
// ---------------------------------------------------------------------------
__global__ void count_kernel(const int* __restrict__ dst, int* __restrict__ counts, int E) {
    int i = blockIdx.x * blockDim.x + threadIdx.x;
    if (i < E) atomicAdd(&counts[dst[i]], 1);
}

__global__ void scan_kernel(const int* __restrict__ counts, int* __restrict__ row_ptr, int n) {
    __shared__ int buf[1024];
    __shared__ int carry_s;
    int t = threadIdx.x;
    if (t == 0) { carry_s = 0; row_ptr[0] = 0; }
    __syncthreads();
    for (int base = 0; base < n; base += 1024) {
        int idx = base + t;
        int v = (idx < n) ? counts[idx] : 0;
        buf[t] = v;
        __syncthreads();
        for (int off = 1; off < 1024; off <<= 1) {
            int add = (t >= off) ? buf[t - off] : 0;
            __syncthreads();
            buf[t] += add;
            __syncthreads();
        }
        int carry = carry_s;
        if (idx < n) row_ptr[idx + 1] = carry + buf[t];
        __syncthreads();
        if (t == 1023) carry_s = carry + buf[1023];
        __syncthreads();
    }
}

__global__ void copy_cursor_kernel(const int* __restrict__ rp, int* __restrict__ cursor, int n) {
    int i = blockIdx.x * blockDim.x + threadIdx.x;
    if (i < n) cursor[i] = rp[i];
}

__global__ void scatter_kernel(const int* __restrict__ src, const int* __restrict__ dst,
                               const float* __restrict__ w, int* __restrict__ cursor,
                               int* __restrict__ csr_src, float* __restrict__ csr_w,
                               int* __restrict__ csr_eid, int E) {
    int i = blockIdx.x * blockDim.x + threadIdx.x;
    if (i < E) {
        int d = dst[i];
        int p = atomicAdd(&cursor[d], 1);
        csr_src[p] = src[i];
        csr_w[p] = w[i];
        csr_eid[p] = i;
    }
}

__global__ void sortrow_kernel(const int* __restrict__ rp, int* __restrict__ csr_src,
                               float* __restrict__ csr_w, int* __restrict__ csr_eid, int n) {
    int r = blockIdx.x * blockDim.x + threadIdx.x;
    if (r >= n) return;
    int s = rp[r], e = rp[r + 1];
    for (int i = s + 1; i < e; ++i) {
        int ke = csr_eid[i]; int ks = csr_src[i]; float kw = csr_w[i];
        int j = i - 1;
        while (j >= s && csr_eid[j] > ke) {
            csr_eid[j + 1] = csr_eid[j];
            csr_src[j + 1] = csr_src[j];
            csr_w[j + 1] = csr_w[j];
            --j;
        }
        csr_eid[j + 1] = ke; csr_src[j + 1] = ks; csr_w[j + 1] = kw;
    }
}

// ---------------------------------------------------------------------------
// Dual GEMM: C[M,384] = X[M,K] @ concat(W, L) [K,384]
//   cols 0..191   -> Hdst (gather source for SPMM)
//   cols 192..383 -> Tdst = acc + bias (+ res row if res != null)
// ---------------------------------------------------------------------------
#define BM 128
#define BN 128
#define BK 16

__global__ __launch_bounds__(256)
void gemm_dual(const float* __restrict__ X, int M, int K,
               const float* __restrict__ W, const float* __restrict__ L,
               const float* __restrict__ bias, const float* __restrict__ res,
               float* __restrict__ Hdst, float* __restrict__ Tdst) {
    __shared__ float As[BK][BM + 4];
    __shared__ float Bs[BK][BN];
    const int m0 = blockIdx.x * BM;
    const int bcol = blockIdx.y * BN;  // 0, 128, 256
    const int tid = threadIdx.x;
    const int tx = tid & 15, ty = tid >> 4;
    float acc[8][8] = {};

    for (int k0 = 0; k0 < K; k0 += BK) {
        // --- load A tile (BM x BK), transposed into LDS ---
        {
            int r = tid >> 1;            // 0..127
            int c0 = (tid & 1) * 8;      // 0 or 8
            int row = m0 + r;
            const float* xp = X + (size_t)row * K + k0 + c0;
            bool rowok = row < M;
#pragma unroll
            for (int j = 0; j < 8; ++j) {
                int kk = k0 + c0 + j;
                float v = (rowok && kk < K) ? xp[j] : 0.f;
                As[c0 + j][r] = v;
            }
        }
        // --- load B tile (BK x BN) from concat(W,L) ---
        {
            int kr = tid >> 4;           // 0..15
            int c = (tid & 15) * 4;      // 0..60
#pragma unroll
            for (int h = 0; h < 2; ++h) {
                int cc = c + h * 64;
                int gc = bcol + cc;
                int krow = k0 + kr;
                float4 v = make_float4(0.f, 0.f, 0.f, 0.f);
                if (krow < K) {
                    const float* bp = (gc < HID) ? (W + (size_t)krow * HID + gc)
                                                 : (L + (size_t)krow * HID + (gc - HID));
                    v = *reinterpret_cast<const float4*>(bp);
                }
                *reinterpret_cast<float4*>(&Bs[kr][cc]) = v;
            }
        }
        __syncthreads();
#pragma unroll
        for (int kk = 0; kk < BK; ++kk) {
            float a[8], b[8];
#pragma unroll
            for (int i = 0; i < 8; ++i) a[i] = As[kk][ty * 8 + i];
#pragma unroll
            for (int j = 0; j < 8; ++j) b[j] = Bs[kk][tx * 8 + j];
#pragma unroll
            for (int i = 0; i < 8; ++i)
#pragma unroll
                for (int j = 0; j < 8; ++j)
                    acc[i][j] += a[i] * b[j];
        }
        __syncthreads();
    }

    // --- epilogue ---
#pragma unroll
    for (int i = 0; i < 8; ++i) {
        int row = m0 + ty * 8 + i;
        if (row >= M) continue;
#pragma unroll
        for (int j = 0; j < 8; ++j) {
            int gc = bcol + tx * 8 + j;
            float v = acc[i][j];
            if (gc < HID) {
                Hdst[(size_t)row * HID + gc] = v;
            } else {
                int c = gc - HID;
                float t = v + bias[c];
                if (res != nullptr) t += res[(size_t)row * HID + c];
                Tdst[(size_t)row * HID + c] = t;
            }
        }
    }
}

// ---------------------------------------------------------------------------
// SPMM: out[n][f] = scale * (out[n][f] + sum_e w_e * H[src_e][f])
// one 64-lane wave per node, 3 column chunks of 64
// ---------------------------------------------------------------------------
__global__ __launch_bounds__(256)
void spmm_kernel(const int* __restrict__ rp, const int* __restrict__ csrc,
                 const float* __restrict__ cw, const float* __restrict__ Hm,
                 float* __restrict__ out, float scale) {
    int wid = (blockIdx.x * 256 + threadIdx.x) >> 6;
    int lane = threadIdx.x & 63;
    if (wid >= N_NODES) return;
    int s = rp[wid], e = rp[wid + 1];
    float a0 = 0.f, a1 = 0.f, a2 = 0.f;
    for (int i = s; i < e; ++i) {
        float w = cw[i];
        int src = csrc[i];
        const float* h = Hm + (size_t)src * HID;
        a0 += w * h[lane];
        a1 += w * h[64 + lane];
        a2 += w * h[128 + lane];
    }
    float* o = out + (size_t)wid * HID;
    o[lane]        = scale * (o[lane] + a0);
    o[64 + lane]   = scale * (o[64 + lane] + a1);
    o[128 + lane]  = scale * (o[128 + lane] + a2);
}

// ---------------------------------------------------------------------------
// Output layer: H3 = x@Wout, T3 = x@Lout + bout   (OUT_DIM = 3)
// one wave per node; then tiny SPMM over 3 cols
// ---------------------------------------------------------------------------
__global__ __launch_bounds__(256)
void out_gemm(const float* __restrict__ X, const float* __restrict__ Wout,
              const float* __restrict__ Lout, const float* __restrict__ bout,
              float* __restrict__ H3, float* __restrict__ T3) {
    __shared__ float Ws[HID * OUT_DIM];
    __shared__ float Ls[HID * OUT_DIM];
    int tid = threadIdx.x;
    for (int i = tid; i < HID * OUT_DIM; i += 256) { Ws[i] = Wout[i]; Ls[i] = Lout[i]; }
    __syncthreads();
    int n = blockIdx.x * 4 + (tid >> 6);
    int lane = tid & 63;
    if (n >= N_NODES) return;
    const float* x = X + (size_t)n * HID;
    float aw[3] = {0.f, 0.f, 0.f}, al[3] = {0.f, 0.f, 0.f};
#pragma unroll
    for (int p = 0; p < 3; ++p) {
        int k = p * 64 + lane;
        float xv = x[k];
#pragma unroll
        for (int c = 0; c < 3; ++c) {
            aw[c] += xv * Ws[k * 3 + c];
            al[c] += xv * Ls[k * 3 + c];
        }
    }
#pragma unroll
    for (int off = 32; off > 0; off >>= 1) {
#pragma unroll
        for (int c = 0; c < 3; ++c) {
            aw[c] += __shfl_down(aw[c], off, 64);
            al[c] += __shfl_down(al[c], off, 64);
        }
    }
    if (lane == 0) {
#pragma unroll
        for (int c = 0; c < 3; ++c) {
            H3[n * 3 + c] = aw[c];
            T3[n * 3 + c] = al[c] + bout[c];
        }
    }
}

__global__ __launch_bounds__(256)
void out_spmm(const int* __restrict__ rp, const int* __restrict__ csrc,
              const float* __restrict__ cw, const float* __restrict__ H3,
              const float* __restrict__ T3, float* __restrict__ out) {
    int n = blockIdx.x * blockDim.x + threadIdx.x;
    if (n >= N_NODES) return;
    int s = rp[n], e = rp[n + 1];
    float a0 = 0.f, a1 = 0.f, a2 = 0.f;
    for (int i = s; i < e; ++i) {
        float w = cw[i];
        int src = csrc[i];
        a0 += w * H3[src * 3 + 0];
        a1 += w * H3[src * 3 + 1];
        a2 += w * H3[src * 3 + 2];
    }
    out[n * 3 + 0] = a0 + T3[n * 3 + 0];
    out[n * 3 + 1] = a1 + T3[n * 3 + 1];
    out[n * 3 + 2] = a2 + T3[n * 3 + 2];
}

// ---------------------------------------------------------------------------
extern "C" void kernel_launch(void* const* d_in, const int* in_sizes, int n_in,
                              void* d_out, int out_size, void* d_ws, size_t ws_size,
                              hipStream_t stream) {
    const float* X0    = (const float*)d_in[0];
    const int*   esrc  = (const int*)d_in[1];
    const int*   edst  = (const int*)d_in[2];
    const float* ew    = (const float*)d_in[3];
    const float* w_in  = (const float*)d_in[4];
    const float* l_in  = (const float*)d_in[5];
    const float* b_in  = (const float*)d_in[6];
    const float* bw    = (const float*)d_in[7];   // [6,2,192,192]
    const float* bl    = (const float*)d_in[8];
    const float* bb    = (const float*)d_in[9];   // [6,2,192]
    const float* w_out = (const float*)d_in[10];
    const float* l_out = (const float*)d_in[11];
    const float* b_out = (const float*)d_in[12];

    char* ws = (char*)d_ws;
    size_t off = 0;
    auto alloc = [&](size_t bytes) -> void* {
        void* p = ws + off;
        off += (bytes + 255) & ~(size_t)255;
        return p;
    };
    float* Hbuf   = (float*)alloc(sizeof(float) * (size_t)N_NODES * HID);
    float* h1     = (float*)alloc(sizeof(float) * (size_t)N_NODES * HID);
    int*   counts = (int*)alloc(sizeof(int) * N_NODES);
    int*   rp     = (int*)alloc(sizeof(int) * (N_NODES + 1));
    int*   cursor = (int*)alloc(sizeof(int) * N_NODES);
    int*   csrc   = (int*)alloc(sizeof(int) * N_EDGES);
    float* cw     = (float*)alloc(sizeof(float) * N_EDGES);
    int*   ceid   = (int*)alloc(sizeof(int) * N_EDGES);
    float* H3     = (float*)alloc(sizeof(float) * (size_t)N_NODES * OUT_DIM);
    float* T3     = (float*)alloc(sizeof(float) * (size_t)N_NODES * OUT_DIM);

    float* xout = (float*)d_out;                  // [N_NODES, 3]
    float* xcat = (float*)d_out + (size_t)N_NODES * OUT_DIM;  // [N_NODES, 192]

    // --- CSR build (deterministic) ---
    hipMemsetAsync(counts, 0, sizeof(int) * N_NODES, stream);
    count_kernel<<<(N_EDGES + 255) / 256, 256, 0, stream>>>(edst, counts, N_EDGES);
    scan_kernel<<<1, 1024, 0, stream>>>(counts, rp, N_NODES);
    copy_cursor_kernel<<<(N_NODES + 255) / 256, 256, 0, stream>>>(rp, cursor, N_NODES);
    scatter_kernel<<<(N_EDGES + 255) / 256, 256, 0, stream>>>(esrc, edst, ew, cursor,
                                                              csrc, cw, ceid, N_EDGES);
    sortrow_kernel<<<(N_NODES + 255) / 256, 256, 0, stream>>>(rp, csrc, cw, ceid, N_NODES);

    dim3 gemm_grid((N_NODES + BM - 1) / BM, 3);
    int spmm_blocks = (N_NODES * 64 + 255) / 256;

    // --- layer 0: x = gconv(X0, w_in, loop_in, b_in) -> xcat ---
    gemm_dual<<<gemm_grid, 256, 0, stream>>>(X0, N_NODES, IN_DIM, w_in, l_in, b_in,
                                             nullptr, Hbuf, xcat);
    spmm_kernel<<<spmm_blocks, 256, 0, stream>>>(rp, csrc, cw, Hbuf, xcat, 1.0f);

    // --- 6 residual blocks ---
    for (int b = 0; b < 6; ++b) {
        const float* W0 = bw + ((size_t)b * 2 + 0) * HID * HID;
        const float* L0 = bl + ((size_t)b * 2 + 0) * HID * HID;
        const float* B0 = bb + ((size_t)b * 2 + 0) * HID;
        const float* W1 = bw + ((size_t)b * 2 + 1) * HID * HID;
        const float* L1 = bl + ((size_t)b * 2 + 1) * HID * HID;
        const float* B1 = bb + ((size_t)b * 2 + 1) * HID;

        // h1 = gconv(xcat)
        gemm_dual<<<gemm_grid, 256, 0, stream>>>(xcat, N_NODES, HID, W0, L0, B0,
                                                 nullptr, Hbuf, h1);
        spmm_kernel<<<spmm_blocks, 256, 0, stream>>>(rp, csrc, cw, Hbuf, h1, 1.0f);
        // xcat = 0.5 * (xcat + gconv(h1))
        gemm_dual<<<gemm_grid, 256, 0, stream>>>(h1, N_NODES, HID, W1, L1, B1,
                                                 xcat, Hbuf, xcat);
        spmm_kernel<<<spmm_blocks, 256, 0, stream>>>(rp, csrc, cw, Hbuf, xcat, 0.5f);
    }

    // --- output layer ---
    out_gemm<<<(N_NODES + 3) / 4, 256, 0, stream>>>(xcat, w_out, l_out, b_out, H3, T3);
    out_spmm<<<(N_NODES + 255) / 256, 256, 0, stream>>>(rp, csrc, cw, H3, T3, xout);
}

// Round 2
// 6344.923 us; speedup vs baseline: 1.3243x; 1.3243x over previous
//
#include <hip/hip_runtime.h>
#include <cstdint>
#include <cstddef>

#define N_NODES 100000
#define N_EDGES 1600000
#define IN_DIM 963
#define HID 192
#define OUT_DIM 3

// ---------------------------------------------------------------------------
// CSR build (deterministic: rows sorted by original edge index)
// ---------------------------------------------------------------------------
__global__ void count_kernel(const int* __restrict__ dst, int* __restrict__ counts, int E) {
    int i = blockIdx.x * blockDim.x + threadIdx.x;
    if (i < E) atomicAdd(&counts[dst[i]], 1);
}

__global__ void scan_kernel(const int* __restrict__ counts, int* __restrict__ row_ptr, int n) {
    __shared__ int buf[1024];
    __shared__ int carry_s;
    int t = threadIdx.x;
    if (t == 0) { carry_s = 0; row_ptr[0] = 0; }
    __syncthreads();
    for (int base = 0; base < n; base += 1024) {
        int idx = base + t;
        int v = (idx < n) ? counts[idx] : 0;
        buf[t] = v;
        __syncthreads();
        for (int off = 1; off < 1024; off <<= 1) {
            int add = (t >= off) ? buf[t - off] : 0;
            __syncthreads();
            buf[t] += add;
            __syncthreads();
        }
        int carry = carry_s;
        if (idx < n) row_ptr[idx + 1] = carry + buf[t];
        __syncthreads();
        if (t == 1023) carry_s = carry + buf[1023];
        __syncthreads();
    }
}

__global__ void copy_cursor_kernel(const int* __restrict__ rp, int* __restrict__ cursor, int n) {
    int i = blockIdx.x * blockDim.x + threadIdx.x;
    if (i < n) cursor[i] = rp[i];
}

__global__ void scatter_kernel(const int* __restrict__ src, const int* __restrict__ dst,
                               const float* __restrict__ w, int* __restrict__ cursor,
                               int* __restrict__ csr_src, float* __restrict__ csr_w,
                               int* __restrict__ csr_eid, int E) {
    int i = blockIdx.x * blockDim.x + threadIdx.x;
    if (i < E) {
        int d = dst[i];
        int p = atomicAdd(&cursor[d], 1);
        csr_src[p] = src[i];
        csr_w[p] = w[i];
        csr_eid[p] = i;
    }
}

__global__ void sortrow_kernel(const int* __restrict__ rp, int* __restrict__ csr_src,
                               float* __restrict__ csr_w, int* __restrict__ csr_eid, int n) {
    int r = blockIdx.x * blockDim.x + threadIdx.x;
    if (r >= n) return;
    int s = rp[r], e = rp[r + 1];
    for (int i = s + 1; i < e; ++i) {
        int ke = csr_eid[i]; int ks = csr_src[i]; float kw = csr_w[i];
        int j = i - 1;
        while (j >= s && csr_eid[j] > ke) {
            csr_eid[j + 1] = csr_eid[j];
            csr_src[j + 1] = csr_src[j];
            csr_w[j + 1] = csr_w[j];
            --j;
        }
        csr_eid[j + 1] = ke; csr_src[j + 1] = ks; csr_w[j + 1] = kw;
    }
}

// ---------------------------------------------------------------------------
// Dual GEMM: C[M,384] = X[M,K] @ concat(W, L) [K,384]
//   cols 0..191   -> Hdst
//   cols 192..383 -> Tdst = acc + bias (+ res)
// 4+4 split micro-tile, float4 LDS reads, register-prefetch double buffer.
// ---------------------------------------------------------------------------
#define BM 128
#define BN 128
#define BK 16

__global__ __launch_bounds__(256)
void gemm_dual(const float* __restrict__ X, int M, int K,
               const float* __restrict__ W, const float* __restrict__ L,
               const float* __restrict__ bias, const float* __restrict__ res,
               float* __restrict__ Hdst, float* __restrict__ Tdst) {
    __shared__ float As[BK][BM];        // transposed A tile
    __shared__ float Bs[BK][BN + 4];    // +4 pad: conflict-free b128 r/w
    const int m0 = blockIdx.x * BM;
    const int bcol = blockIdx.y * BN;   // 0, 128, 256
    const int tid = threadIdx.x;
    const int tx = tid & 15, ty = tid >> 4;

    // A staging: thread -> row (tid>>1), 8 cols at (tid&1)*8
    const int ar = tid >> 1;
    const int ac = (tid & 1) * 8;
    const int arow = m0 + ar;
    const bool arok = arow < M;
    const float* xrow = X + (size_t)(arok ? arow : 0) * K;

    // B staging: thread -> k-row (tid>>4), float4 cols at (tid&15)*4 and +64
    const int bkr = tid >> 4;
    const int bc0 = (tid & 15) * 4;
    const int gc0 = bcol + bc0;
    const int gc1 = bcol + bc0 + 64;
    const float* bp0 = (gc0 < HID) ? (W + gc0) : (L + (gc0 - HID));
    const float* bp1 = (gc1 < HID) ? (W + gc1) : (L + (gc1 - HID));

    float4 pa0, pa1, pb0, pb1;
    const float4 f4z = make_float4(0.f, 0.f, 0.f, 0.f);

    auto loadA = [&](int k0) {
        if (k0 + BK <= K) {
            if (arok) {
                pa0 = *reinterpret_cast<const float4*>(xrow + k0 + ac);
                pa1 = *reinterpret_cast<const float4*>(xrow + k0 + ac + 4);
            } else { pa0 = f4z; pa1 = f4z; }
        } else {
            float t[8];
#pragma unroll
            for (int j = 0; j < 8; ++j) {
                int kk = k0 + ac + j;
                t[j] = (arok && kk < K) ? xrow[kk] : 0.f;
            }
            pa0 = make_float4(t[0], t[1], t[2], t[3]);
            pa1 = make_float4(t[4], t[5], t[6], t[7]);
        }
    };
    auto loadB = [&](int k0) {
        int krow = k0 + bkr;
        if (krow < K) {
            pb0 = *reinterpret_cast<const float4*>(bp0 + (size_t)krow * HID);
            pb1 = *reinterpret_cast<const float4*>(bp1 + (size_t)krow * HID);
        } else { pb0 = f4z; pb1 = f4z; }
    };
    auto stash = [&]() {
        As[ac + 0][ar] = pa0.x; As[ac + 1][ar] = pa0.y;
        As[ac + 2][ar] = pa0.z; As[ac + 3][ar] = pa0.w;
        As[ac + 4][ar] = pa1.x; As[ac + 5][ar] = pa1.y;
        As[ac + 6][ar] = pa1.z; As[ac + 7][ar] = pa1.w;
        *reinterpret_cast<float4*>(&Bs[bkr][bc0]) = pb0;
        *reinterpret_cast<float4*>(&Bs[bkr][bc0 + 64]) = pb1;
    };

    float acc[8][8] = {};

    loadA(0); loadB(0);
    stash();
    __syncthreads();

    for (int k0 = 0; k0 < K; k0 += BK) {
        const bool more = (k0 + BK) < K;
        if (more) { loadA(k0 + BK); loadB(k0 + BK); }   // overlap with compute
#pragma unroll
        for (int kk = 0; kk < BK; ++kk) {
            float4 a0 = *reinterpret_cast<const float4*>(&As[kk][ty * 4]);
            float4 a1 = *reinterpret_cast<const float4*>(&As[kk][ty * 4 + 64]);
            float4 b0 = *reinterpret_cast<const float4*>(&Bs[kk][tx * 4]);
            float4 b1 = *reinterpret_cast<const float4*>(&Bs[kk][tx * 4 + 64]);
            float a[8] = {a0.x, a0.y, a0.z, a0.w, a1.x, a1.y, a1.z, a1.w};
            float b[8] = {b0.x, b0.y, b0.z, b0.w, b1.x, b1.y, b1.z, b1.w};
#pragma unroll
            for (int i = 0; i < 8; ++i)
#pragma unroll
                for (int j = 0; j < 8; ++j)
                    acc[i][j] += a[i] * b[j];
        }
        if (more) {
            __syncthreads();
            stash();
            __syncthreads();
        }
    }

    // --- epilogue: float4 stores; dest (H vs T) is uniform per column group ---
#pragma unroll
    for (int g = 0; g < 2; ++g) {
        const int gc = bcol + g * 64 + tx * 4;
        const bool isH = gc < HID;
        const int c = isH ? gc : gc - HID;
        float4 bv = f4z;
        if (!isH) bv = *reinterpret_cast<const float4*>(&bias[c]);
#pragma unroll
        for (int half = 0; half < 2; ++half) {
#pragma unroll
            for (int i = 0; i < 4; ++i) {
                const int row = m0 + half * 64 + ty * 4 + i;
                if (row >= M) continue;
                const int ai = half * 4 + i;
                float4 v = make_float4(acc[ai][g * 4 + 0], acc[ai][g * 4 + 1],
                                       acc[ai][g * 4 + 2], acc[ai][g * 4 + 3]);
                if (isH) {
                    *reinterpret_cast<float4*>(&Hdst[(size_t)row * HID + c]) = v;
                } else {
                    float4 t = make_float4(v.x + bv.x, v.y + bv.y, v.z + bv.z, v.w + bv.w);
                    if (res != nullptr) {
                        float4 r = *reinterpret_cast<const float4*>(&res[(size_t)row * HID + c]);
                        t.x += r.x; t.y += r.y; t.z += r.z; t.w += r.w;
                    }
                    *reinterpret_cast<float4*>(&Tdst[(size_t)row * HID + c]) = t;
                }
            }
        }
    }
}

// ---------------------------------------------------------------------------
// SPMM: out[n][f] = scale * (out[n][f] + sum_e w_e * H[src_e][f])
// one 64-lane wave per node; 2-edge unroll for ILP
// ---------------------------------------------------------------------------
__global__ __launch_bounds__(256)
void spmm_kernel(const int* __restrict__ rp, const int* __restrict__ csrc,
                 const float* __restrict__ cw, const float* __restrict__ Hm,
                 float* __restrict__ out, float scale) {
    int wid = (blockIdx.x * 256 + threadIdx.x) >> 6;
    int lane = threadIdx.x & 63;
    if (wid >= N_NODES) return;
    int s = rp[wid], e = rp[wid + 1];
    float a0 = 0.f, a1 = 0.f, a2 = 0.f;
    int i = s;
    for (; i + 1 < e; i += 2) {
        float w0 = cw[i], w1 = cw[i + 1];
        const float* h0 = Hm + (size_t)csrc[i] * HID;
        const float* h1 = Hm + (size_t)csrc[i + 1] * HID;
        float x00 = h0[lane], x01 = h0[64 + lane], x02 = h0[128 + lane];
        float x10 = h1[lane], x11 = h1[64 + lane], x12 = h1[128 + lane];
        a0 += w0 * x00; a1 += w0 * x01; a2 += w0 * x02;
        a0 += w1 * x10; a1 += w1 * x11; a2 += w1 * x12;
    }
    if (i < e) {
        float w = cw[i];
        const float* h = Hm + (size_t)csrc[i] * HID;
        a0 += w * h[lane];
        a1 += w * h[64 + lane];
        a2 += w * h[128 + lane];
    }
    float* o = out + (size_t)wid * HID;
    o[lane]       = scale * (o[lane] + a0);
    o[64 + lane]  = scale * (o[64 + lane] + a1);
    o[128 + lane] = scale * (o[128 + lane] + a2);
}

// ---------------------------------------------------------------------------
// Output layer
// ---------------------------------------------------------------------------
__global__ __launch_bounds__(256)
void out_gemm(const float* __restrict__ X, const float* __restrict__ Wout,
              const float* __restrict__ Lout, const float* __restrict__ bout,
              float* __restrict__ H3, float* __restrict__ T3) {
    __shared__ float Ws[HID * OUT_DIM];
    __shared__ float Ls[HID * OUT_DIM];
    int tid = threadIdx.x;
    for (int i = tid; i < HID * OUT_DIM; i += 256) { Ws[i] = Wout[i]; Ls[i] = Lout[i]; }
    __syncthreads();
    int n = blockIdx.x * 4 + (tid >> 6);
    int lane = tid & 63;
    if (n >= N_NODES) return;
    const float* x = X + (size_t)n * HID;
    float aw[3] = {0.f, 0.f, 0.f}, al[3] = {0.f, 0.f, 0.f};
#pragma unroll
    for (int p = 0; p < 3; ++p) {
        int k = p * 64 + lane;
        float xv = x[k];
#pragma unroll
        for (int c = 0; c < 3; ++c) {
            aw[c] += xv * Ws[k * 3 + c];
            al[c] += xv * Ls[k * 3 + c];
        }
    }
#pragma unroll
    for (int off = 32; off > 0; off >>= 1) {
#pragma unroll
        for (int c = 0; c < 3; ++c) {
            aw[c] += __shfl_down(aw[c], off, 64);
            al[c] += __shfl_down(al[c], off, 64);
        }
    }
    if (lane == 0) {
#pragma unroll
        for (int c = 0; c < 3; ++c) {
            H3[n * 3 + c] = aw[c];
            T3[n * 3 + c] = al[c] + bout[c];
        }
    }
}

__global__ __launch_bounds__(256)
void out_spmm(const int* __restrict__ rp, const int* __restrict__ csrc,
              const float* __restrict__ cw, const float* __restrict__ H3,
              const float* __restrict__ T3, float* __restrict__ out) {
    int n = blockIdx.x * blockDim.x + threadIdx.x;
    if (n >= N_NODES) return;
    int s = rp[n], e = rp[n + 1];
    float a0 = 0.f, a1 = 0.f, a2 = 0.f;
    for (int i = s; i < e; ++i) {
        float w = cw[i];
        int src = csrc[i];
        a0 += w * H3[src * 3 + 0];
        a1 += w * H3[src * 3 + 1];
        a2 += w * H3[src * 3 + 2];
    }
    out[n * 3 + 0] = a0 + T3[n * 3 + 0];
    out[n * 3 + 1] = a1 + T3[n * 3 + 1];
    out[n * 3 + 2] = a2 + T3[n * 3 + 2];
}

// ---------------------------------------------------------------------------
extern "C" void kernel_launch(void* const* d_in, const int* in_sizes, int n_in,
                              void* d_out, int out_size, void* d_ws, size_t ws_size,
                              hipStream_t stream) {
    const float* X0    = (const float*)d_in[0];
    const int*   esrc  = (const int*)d_in[1];
    const int*   edst  = (const int*)d_in[2];
    const float* ew    = (const float*)d_in[3];
    const float* w_in  = (const float*)d_in[4];
    const float* l_in  = (const float*)d_in[5];
    const float* b_in  = (const float*)d_in[6];
    const float* bw    = (const float*)d_in[7];   // [6,2,192,192]
    const float* bl    = (const float*)d_in[8];
    const float* bb    = (const float*)d_in[9];   // [6,2,192]
    const float* w_out = (const float*)d_in[10];
    const float* l_out = (const float*)d_in[11];
    const float* b_out = (const float*)d_in[12];

    char* ws = (char*)d_ws;
    size_t off = 0;
    auto alloc = [&](size_t bytes) -> void* {
        void* p = ws + off;
        off += (bytes + 255) & ~(size_t)255;
        return p;
    };
    float* Hbuf   = (float*)alloc(sizeof(float) * (size_t)N_NODES * HID);
    float* h1     = (float*)alloc(sizeof(float) * (size_t)N_NODES * HID);
    int*   counts = (int*)alloc(sizeof(int) * N_NODES);
    int*   rp     = (int*)alloc(sizeof(int) * (N_NODES + 1));
    int*   cursor = (int*)alloc(sizeof(int) * N_NODES);
    int*   csrc   = (int*)alloc(sizeof(int) * N_EDGES);
    float* cw     = (float*)alloc(sizeof(float) * N_EDGES);
    int*   ceid   = (int*)alloc(sizeof(int) * N_EDGES);
    float* H3     = (float*)alloc(sizeof(float) * (size_t)N_NODES * OUT_DIM);
    float* T3     = (float*)alloc(sizeof(float) * (size_t)N_NODES * OUT_DIM);

    float* xout = (float*)d_out;                  // [N_NODES, 3]
    float* xcat = (float*)d_out + (size_t)N_NODES * OUT_DIM;  // [N_NODES, 192]

    // --- CSR build (deterministic) ---
    hipMemsetAsync(counts, 0, sizeof(int) * N_NODES, stream);
    count_kernel<<<(N_EDGES + 255) / 256, 256, 0, stream>>>(edst, counts, N_EDGES);
    scan_kernel<<<1, 1024, 0, stream>>>(counts, rp, N_NODES);
    copy_cursor_kernel<<<(N_NODES + 255) / 256, 256, 0, stream>>>(rp, cursor, N_NODES);
    scatter_kernel<<<(N_EDGES + 255) / 256, 256, 0, stream>>>(esrc, edst, ew, cursor,
                                                              csrc, cw, ceid, N_EDGES);
    sortrow_kernel<<<(N_NODES + 255) / 256, 256, 0, stream>>>(rp, csrc, cw, ceid, N_NODES);

    dim3 gemm_grid((N_NODES + BM - 1) / BM, 3);
    int spmm_blocks = (N_NODES * 64 + 255) / 256;

    // --- layer 0 ---
    gemm_dual<<<gemm_grid, 256, 0, stream>>>(X0, N_NODES, IN_DIM, w_in, l_in, b_in,
                                             nullptr, Hbuf, xcat);
    spmm_kernel<<<spmm_blocks, 256, 0, stream>>>(rp, csrc, cw, Hbuf, xcat, 1.0f);

    // --- 6 residual blocks ---
    for (int b = 0; b < 6; ++b) {
        const float* W0 = bw + ((size_t)b * 2 + 0) * HID * HID;
        const float* L0 = bl + ((size_t)b * 2 + 0) * HID * HID;
        const float* B0 = bb + ((size_t)b * 2 + 0) * HID;
        const float* W1 = bw + ((size_t)b * 2 + 1) * HID * HID;
        const float* L1 = bl + ((size_t)b * 2 + 1) * HID * HID;
        const float* B1 = bb + ((size_t)b * 2 + 1) * HID;

        gemm_dual<<<gemm_grid, 256, 0, stream>>>(xcat, N_NODES, HID, W0, L0, B0,
                                                 nullptr, Hbuf, h1);
        spmm_kernel<<<spmm_blocks, 256, 0, stream>>>(rp, csrc, cw, Hbuf, h1, 1.0f);
        gemm_dual<<<gemm_grid, 256, 0, stream>>>(h1, N_NODES, HID, W1, L1, B1,
                                                 xcat, Hbuf, xcat);
        spmm_kernel<<<spmm_blocks, 256, 0, stream>>>(rp, csrc, cw, Hbuf, xcat, 0.5f);
    }

    // --- output layer ---
    out_gemm<<<(N_NODES + 3) / 4, 256, 0, stream>>>(xcat, w_out, l_out, b_out, H3, T3);
    out_spmm<<<(N_NODES + 255) / 256, 256, 0, stream>>>(rp, csrc, cw, H3, T3, xout);
}

// Round 3
// 4515.611 us; speedup vs baseline: 1.8607x; 1.4051x over previous
//
#include <hip/hip_runtime.h>
#include <cstdint>
#include <cstddef>

#define N_NODES 100000
#define N_EDGES 1600000
#define IN_DIM 963
#define HID 192
#define OUT_DIM 3

typedef _Float16 f16x8 __attribute__((ext_vector_type(8)));
typedef _Float16 f16x4 __attribute__((ext_vector_type(4)));
typedef float f32x4 __attribute__((ext_vector_type(4)));

// ---------------------------------------------------------------------------
// CSR build (deterministic: rows sorted by original edge index)
// ---------------------------------------------------------------------------
__global__ void count_kernel(const int* __restrict__ dst, int* __restrict__ counts, int E) {
    int i = blockIdx.x * blockDim.x + threadIdx.x;
    if (i < E) atomicAdd(&counts[dst[i]], 1);
}

__global__ void scan_kernel(const int* __restrict__ counts, int* __restrict__ row_ptr, int n) {
    __shared__ int buf[1024];
    __shared__ int carry_s;
    int t = threadIdx.x;
    if (t == 0) { carry_s = 0; row_ptr[0] = 0; }
    __syncthreads();
    for (int base = 0; base < n; base += 1024) {
        int idx = base + t;
        int v = (idx < n) ? counts[idx] : 0;
        buf[t] = v;
        __syncthreads();
        for (int off = 1; off < 1024; off <<= 1) {
            int add = (t >= off) ? buf[t - off] : 0;
            __syncthreads();
            buf[t] += add;
            __syncthreads();
        }
        int carry = carry_s;
        if (idx < n) row_ptr[idx + 1] = carry + buf[t];
        __syncthreads();
        if (t == 1023) carry_s = carry + buf[1023];
        __syncthreads();
    }
}

__global__ void copy_cursor_kernel(const int* __restrict__ rp, int* __restrict__ cursor, int n) {
    int i = blockIdx.x * blockDim.x + threadIdx.x;
    if (i < n) cursor[i] = rp[i];
}

__global__ void scatter_kernel(const int* __restrict__ src, const int* __restrict__ dst,
                               const float* __restrict__ w, int* __restrict__ cursor,
                               int* __restrict__ csr_src, float* __restrict__ csr_w,
                               int* __restrict__ csr_eid, int E) {
    int i = blockIdx.x * blockDim.x + threadIdx.x;
    if (i < E) {
        int d = dst[i];
        int p = atomicAdd(&cursor[d], 1);
        csr_src[p] = src[i];
        csr_w[p] = w[i];
        csr_eid[p] = i;
    }
}

__global__ void sortrow_kernel(const int* __restrict__ rp, int* __restrict__ csr_src,
                               float* __restrict__ csr_w, int* __restrict__ csr_eid, int n) {
    int r = blockIdx.x * blockDim.x + threadIdx.x;
    if (r >= n) return;
    int s = rp[r], e = rp[r + 1];
    for (int i = s + 1; i < e; ++i) {
        int ke = csr_eid[i]; int ks = csr_src[i]; float kw = csr_w[i];
        int j = i - 1;
        while (j >= s && csr_eid[j] > ke) {
            csr_eid[j + 1] = csr_eid[j];
            csr_src[j + 1] = csr_src[j];
            csr_w[j + 1] = csr_w[j];
            --j;
        }
        csr_eid[j + 1] = ke; csr_src[j + 1] = ks; csr_w[j + 1] = kw;
    }
}

// ---------------------------------------------------------------------------
// Weight transpose + fp16 hi/lo split:  in W[K][192], L[K][192] (f32)
//   -> out_hi/out_lo [384][Kp] (f16), zero-padded to Kp
// ---------------------------------------------------------------------------
__global__ __launch_bounds__(256)
void trans_split(const float* __restrict__ W, const float* __restrict__ L,
                 int K, int Kp, _Float16* __restrict__ out_hi, _Float16* __restrict__ out_lo) {
    __shared__ float tile[32][33];
    const int n0 = blockIdx.x * 32, k0 = blockIdx.y * 32;
    const int tx = threadIdx.x, ty = threadIdx.y;   // (32, 8)
#pragma unroll
    for (int i = 0; i < 4; ++i) {
        int k = k0 + ty + i * 8;
        int n = n0 + tx;
        float v = 0.f;
        if (k < K) v = (n < HID) ? W[(size_t)k * HID + n] : L[(size_t)k * HID + (n - HID)];
        tile[ty + i * 8][tx] = v;
    }
    __syncthreads();
#pragma unroll
    for (int i = 0; i < 4; ++i) {
        int nl = ty + i * 8;
        int n = n0 + nl;
        int k = k0 + tx;
        float v = tile[tx][nl];
        _Float16 hi = (_Float16)v;
        _Float16 lo = (_Float16)(v - (float)hi);
        out_hi[(size_t)n * Kp + k] = hi;
        out_lo[(size_t)n * Kp + k] = lo;
    }
}

// ---------------------------------------------------------------------------
// MFMA dual GEMM (fp16x3 split): C[M,384] = X[M,Kx] @ Wt^T
//   Wt_hi/lo: [384][Kp] f16 (pre-transposed, k-contiguous)
//   cols 0..191 -> Hdst ; cols 192..383 -> Tdst = acc + bias (+ res)
// Block: 256 thr = 4 waves, tile 128x128, BK=32. Wave -> 64x64 (4x4 frags).
// LDS layout per buffer (4096 halves): frag f, lane l -> halves [f*512 + l*8 .. +7]
//   element (idx, k): off = (idx>>4)*512 + (k>>3)*128 + ((idx&15)^(k>>3))*8 + (k&7)
// ---------------------------------------------------------------------------
__global__ __launch_bounds__(256, 2)
void gemm_mfma(const float* __restrict__ X, int M, int Kx, int Kp,
               const _Float16* __restrict__ Wth, const _Float16* __restrict__ Wtl,
               const float* __restrict__ bias, const float* __restrict__ res,
               float* __restrict__ Hdst, float* __restrict__ Tdst) {
    __shared__ __align__(16) _Float16 Ah[4096];
    __shared__ __align__(16) _Float16 Al[4096];
    __shared__ __align__(16) _Float16 Bh[4096];
    __shared__ __align__(16) _Float16 Bl[4096];

    const int m0 = blockIdx.x * 128;
    const int bcol = blockIdx.y * 128;
    const int tid = threadIdx.x;
    const int lane = tid & 63;
    const int wave = tid >> 6;
    const int wr = wave >> 1, wc = wave & 1;

    // A staging: thread -> row sr, k-half sh (16 k each)
    const int sr = tid >> 1;
    const int sh = tid & 1;
    const int arow = m0 + sr;
    const bool arok = arow < M;
    const float* xrow = X + (size_t)(arok ? arow : 0) * Kx;

    // B staging: 4 iters; it<2 -> hi buf, else lo. nl = (it&1)*64 + (tid>>2), q = tid&3
    const int bnl_lo = tid >> 2;
    const int bq = tid & 3;

    f32x4 pa[4];
    f16x8 pb[4];

    auto loadA = [&](int k0) {
        if (arok && (k0 + 32) <= Kx) {
            const float* p = xrow + k0 + sh * 16;
            pa[0] = *(const f32x4*)(p);
            pa[1] = *(const f32x4*)(p + 4);
            pa[2] = *(const f32x4*)(p + 8);
            pa[3] = *(const f32x4*)(p + 12);
        } else {
#pragma unroll
            for (int c = 0; c < 4; ++c) {
                f32x4 v = {0.f, 0.f, 0.f, 0.f};
#pragma unroll
                for (int j = 0; j < 4; ++j) {
                    int k = k0 + sh * 16 + c * 4 + j;
                    if (arok && k < Kx) v[j] = xrow[k];
                }
                pa[c] = v;
            }
        }
    };
    auto loadB = [&](int k0) {
#pragma unroll
        for (int it = 0; it < 4; ++it) {
            const _Float16* srcp = (it < 2) ? Wth : Wtl;
            int nl = (it & 1) * 64 + bnl_lo;
            pb[it] = *(const f16x8*)(srcp + (size_t)(bcol + nl) * Kp + k0 + bq * 8);
        }
    };
    auto stashA = [&]() {
#pragma unroll
        for (int c = 0; c < 2; ++c) {
            f16x8 hi, lo;
#pragma unroll
            for (int j = 0; j < 8; ++j) {
                int e = c * 8 + j;
                float x = pa[e >> 2][e & 3];
                _Float16 h = (_Float16)x;
                hi[j] = h;
                lo[j] = (_Float16)(x - (float)h);
            }
            int kg = sh * 2 + c;
            int off = (sr >> 4) * 512 + kg * 128 + ((sr & 15) ^ kg) * 8;
            *(f16x8*)&Ah[off] = hi;
            *(f16x8*)&Al[off] = lo;
        }
    };
    auto stashB = [&]() {
#pragma unroll
        for (int it = 0; it < 4; ++it) {
            int nl = (it & 1) * 64 + bnl_lo;
            int off = (nl >> 4) * 512 + bq * 128 + ((nl & 15) ^ bq) * 8;
            _Float16* dst = (it < 2) ? Bh : Bl;
            *(f16x8*)&dst[off] = pb[it];
        }
    };

    f32x4 acc[4][4];
#pragma unroll
    for (int i = 0; i < 4; ++i)
#pragma unroll
        for (int j = 0; j < 4; ++j)
            acc[i][j] = f32x4{0.f, 0.f, 0.f, 0.f};

    const int lro = (lane >> 4) * 128 + ((lane & 15) ^ (lane >> 4)) * 8;

    loadA(0); loadB(0);
    for (int k0 = 0; k0 < Kx; k0 += 32) {
        stashA(); stashB();
        __syncthreads();
        if (k0 + 32 < Kx) { loadA(k0 + 32); loadB(k0 + 32); }
        f16x8 ah[4], al[4], bh[4], bl[4];
#pragma unroll
        for (int i = 0; i < 4; ++i) {
            ah[i] = *(const f16x8*)&Ah[(wr * 4 + i) * 512 + lro];
            al[i] = *(const f16x8*)&Al[(wr * 4 + i) * 512 + lro];
            bh[i] = *(const f16x8*)&Bh[(wc * 4 + i) * 512 + lro];
            bl[i] = *(const f16x8*)&Bl[(wc * 4 + i) * 512 + lro];
        }
#pragma unroll
        for (int mi = 0; mi < 4; ++mi)
#pragma unroll
            for (int ni = 0; ni < 4; ++ni) {
                acc[mi][ni] = __builtin_amdgcn_mfma_f32_16x16x32_f16(ah[mi], bh[ni], acc[mi][ni], 0, 0, 0);
                acc[mi][ni] = __builtin_amdgcn_mfma_f32_16x16x32_f16(al[mi], bh[ni], acc[mi][ni], 0, 0, 0);
                acc[mi][ni] = __builtin_amdgcn_mfma_f32_16x16x32_f16(ah[mi], bl[ni], acc[mi][ni], 0, 0, 0);
            }
        __syncthreads();
    }

    // epilogue: C/D layout col = lane&15, row = (lane>>4)*4 + j
#pragma unroll
    for (int mi = 0; mi < 4; ++mi) {
        int rbase = m0 + wr * 64 + mi * 16 + ((lane >> 4) << 2);
#pragma unroll
        for (int ni = 0; ni < 4; ++ni) {
            int gc = bcol + wc * 64 + ni * 16 + (lane & 15);
            f32x4 v = acc[mi][ni];
            if (gc < HID) {
#pragma unroll
                for (int j = 0; j < 4; ++j) {
                    int row = rbase + j;
                    if (row < M) Hdst[(size_t)row * HID + gc] = v[j];
                }
            } else {
                int c = gc - HID;
                float bv = bias[c];
#pragma unroll
                for (int j = 0; j < 4; ++j) {
                    int row = rbase + j;
                    if (row < M) {
                        float t = v[j] + bv;
                        if (res != nullptr) t += res[(size_t)row * HID + c];
                        Tdst[(size_t)row * HID + c] = t;
                    }
                }
            }
        }
    }
}

// ---------------------------------------------------------------------------
// SPMM: out[n][f] = scale * (out[n][f] + sum_e w_e * H[src_e][f])
// ---------------------------------------------------------------------------
__global__ __launch_bounds__(256)
void spmm_kernel(const int* __restrict__ rp, const int* __restrict__ csrc,
                 const float* __restrict__ cw, const float* __restrict__ Hm,
                 float* __restrict__ out, float scale) {
    int wid = (blockIdx.x * 256 + threadIdx.x) >> 6;
    int lane = threadIdx.x & 63;
    if (wid >= N_NODES) return;
    int s = rp[wid], e = rp[wid + 1];
    float a0 = 0.f, a1 = 0.f, a2 = 0.f;
    int i = s;
    for (; i + 1 < e; i += 2) {
        float w0 = cw[i], w1 = cw[i + 1];
        const float* h0 = Hm + (size_t)csrc[i] * HID;
        const float* h1 = Hm + (size_t)csrc[i + 1] * HID;
        float x00 = h0[lane], x01 = h0[64 + lane], x02 = h0[128 + lane];
        float x10 = h1[lane], x11 = h1[64 + lane], x12 = h1[128 + lane];
        a0 += w0 * x00; a1 += w0 * x01; a2 += w0 * x02;
        a0 += w1 * x10; a1 += w1 * x11; a2 += w1 * x12;
    }
    if (i < e) {
        float w = cw[i];
        const float* h = Hm + (size_t)csrc[i] * HID;
        a0 += w * h[lane];
        a1 += w * h[64 + lane];
        a2 += w * h[128 + lane];
    }
    float* o = out + (size_t)wid * HID;
    o[lane]       = scale * (o[lane] + a0);
    o[64 + lane]  = scale * (o[64 + lane] + a1);
    o[128 + lane] = scale * (o[128 + lane] + a2);
}

// ---------------------------------------------------------------------------
// Output layer
// ---------------------------------------------------------------------------
__global__ __launch_bounds__(256)
void out_gemm(const float* __restrict__ X, const float* __restrict__ Wout,
              const float* __restrict__ Lout, const float* __restrict__ bout,
              float* __restrict__ H3, float* __restrict__ T3) {
    __shared__ float Ws[HID * OUT_DIM];
    __shared__ float Ls[HID * OUT_DIM];
    int tid = threadIdx.x;
    for (int i = tid; i < HID * OUT_DIM; i += 256) { Ws[i] = Wout[i]; Ls[i] = Lout[i]; }
    __syncthreads();
    int n = blockIdx.x * 4 + (tid >> 6);
    int lane = tid & 63;
    if (n >= N_NODES) return;
    const float* x = X + (size_t)n * HID;
    float aw[3] = {0.f, 0.f, 0.f}, al[3] = {0.f, 0.f, 0.f};
#pragma unroll
    for (int p = 0; p < 3; ++p) {
        int k = p * 64 + lane;
        float xv = x[k];
#pragma unroll
        for (int c = 0; c < 3; ++c) {
            aw[c] += xv * Ws[k * 3 + c];
            al[c] += xv * Ls[k * 3 + c];
        }
    }
#pragma unroll
    for (int off = 32; off > 0; off >>= 1) {
#pragma unroll
        for (int c = 0; c < 3; ++c) {
            aw[c] += __shfl_down(aw[c], off, 64);
            al[c] += __shfl_down(al[c], off, 64);
        }
    }
    if (lane == 0) {
#pragma unroll
        for (int c = 0; c < 3; ++c) {
            H3[n * 3 + c] = aw[c];
            T3[n * 3 + c] = al[c] + bout[c];
        }
    }
}

__global__ __launch_bounds__(256)
void out_spmm(const int* __restrict__ rp, const int* __restrict__ csrc,
              const float* __restrict__ cw, const float* __restrict__ H3,
              const float* __restrict__ T3, float* __restrict__ out) {
    int n = blockIdx.x * blockDim.x + threadIdx.x;
    if (n >= N_NODES) return;
    int s = rp[n], e = rp[n + 1];
    float a0 = 0.f, a1 = 0.f, a2 = 0.f;
    for (int i = s; i < e; ++i) {
        float w = cw[i];
        int src = csrc[i];
        a0 += w * H3[src * 3 + 0];
        a1 += w * H3[src * 3 + 1];
        a2 += w * H3[src * 3 + 2];
    }
    out[n * 3 + 0] = a0 + T3[n * 3 + 0];
    out[n * 3 + 1] = a1 + T3[n * 3 + 1];
    out[n * 3 + 2] = a2 + T3[n * 3 + 2];
}

// ---------------------------------------------------------------------------
extern "C" void kernel_launch(void* const* d_in, const int* in_sizes, int n_in,
                              void* d_out, int out_size, void* d_ws, size_t ws_size,
                              hipStream_t stream) {
    const float* X0    = (const float*)d_in[0];
    const int*   esrc  = (const int*)d_in[1];
    const int*   edst  = (const int*)d_in[2];
    const float* ew    = (const float*)d_in[3];
    const float* w_in  = (const float*)d_in[4];
    const float* l_in  = (const float*)d_in[5];
    const float* b_in  = (const float*)d_in[6];
    const float* bw    = (const float*)d_in[7];   // [6,2,192,192]
    const float* bl    = (const float*)d_in[8];
    const float* bb    = (const float*)d_in[9];   // [6,2,192]
    const float* w_out = (const float*)d_in[10];
    const float* l_out = (const float*)d_in[11];
    const float* b_out = (const float*)d_in[12];

    char* ws = (char*)d_ws;
    size_t off = 0;
    auto alloc = [&](size_t bytes) -> void* {
        void* p = ws + off;
        off += (bytes + 255) & ~(size_t)255;
        return p;
    };
    float* Hbuf   = (float*)alloc(sizeof(float) * (size_t)N_NODES * HID);
    float* h1     = (float*)alloc(sizeof(float) * (size_t)N_NODES * HID);
    int*   counts = (int*)alloc(sizeof(int) * N_NODES);
    int*   rp     = (int*)alloc(sizeof(int) * (N_NODES + 1));
    int*   cursor = (int*)alloc(sizeof(int) * N_NODES);
    int*   csrc   = (int*)alloc(sizeof(int) * N_EDGES);
    float* cw     = (float*)alloc(sizeof(float) * N_EDGES);
    int*   ceid   = (int*)alloc(sizeof(int) * N_EDGES);
    float* H3     = (float*)alloc(sizeof(float) * (size_t)N_NODES * OUT_DIM);
    float* T3     = (float*)alloc(sizeof(float) * (size_t)N_NODES * OUT_DIM);
    const int KP0 = 992;
    _Float16* Wt0h = (_Float16*)alloc(sizeof(_Float16) * 384 * KP0);
    _Float16* Wt0l = (_Float16*)alloc(sizeof(_Float16) * 384 * KP0);
    _Float16* WtHh = (_Float16*)alloc(sizeof(_Float16) * 12 * 384 * HID);
    _Float16* WtHl = (_Float16*)alloc(sizeof(_Float16) * 12 * 384 * HID);

    float* xout = (float*)d_out;                  // [N_NODES, 3]
    float* xcat = (float*)d_out + (size_t)N_NODES * OUT_DIM;  // [N_NODES, 192]

    // --- weight transpose + split (all layers, up front) ---
    trans_split<<<dim3(12, 31), dim3(32, 8), 0, stream>>>(w_in, l_in, IN_DIM, KP0, Wt0h, Wt0l);
    for (int l = 0; l < 12; ++l) {
        trans_split<<<dim3(12, 6), dim3(32, 8), 0, stream>>>(
            bw + (size_t)l * HID * HID, bl + (size_t)l * HID * HID, HID, HID,
            WtHh + (size_t)l * 384 * HID, WtHl + (size_t)l * 384 * HID);
    }

    // --- CSR build (deterministic) ---
    hipMemsetAsync(counts, 0, sizeof(int) * N_NODES, stream);
    count_kernel<<<(N_EDGES + 255) / 256, 256, 0, stream>>>(edst, counts, N_EDGES);
    scan_kernel<<<1, 1024, 0, stream>>>(counts, rp, N_NODES);
    copy_cursor_kernel<<<(N_NODES + 255) / 256, 256, 0, stream>>>(rp, cursor, N_NODES);
    scatter_kernel<<<(N_EDGES + 255) / 256, 256, 0, stream>>>(esrc, edst, ew, cursor,
                                                              csrc, cw, ceid, N_EDGES);
    sortrow_kernel<<<(N_NODES + 255) / 256, 256, 0, stream>>>(rp, csrc, cw, ceid, N_NODES);

    dim3 gemm_grid((N_NODES + 127) / 128, 3);
    int spmm_blocks = (N_NODES * 64 + 255) / 256;

    // --- layer 0 ---
    gemm_mfma<<<gemm_grid, 256, 0, stream>>>(X0, N_NODES, IN_DIM, KP0, Wt0h, Wt0l,
                                             b_in, nullptr, Hbuf, xcat);
    spmm_kernel<<<spmm_blocks, 256, 0, stream>>>(rp, csrc, cw, Hbuf, xcat, 1.0f);

    // --- 6 residual blocks ---
    for (int b = 0; b < 6; ++b) {
        int l0 = b * 2, l1 = b * 2 + 1;
        const float* B0 = bb + (size_t)l0 * HID;
        const float* B1 = bb + (size_t)l1 * HID;

        gemm_mfma<<<gemm_grid, 256, 0, stream>>>(xcat, N_NODES, HID, HID,
                                                 WtHh + (size_t)l0 * 384 * HID,
                                                 WtHl + (size_t)l0 * 384 * HID,
                                                 B0, nullptr, Hbuf, h1);
        spmm_kernel<<<spmm_blocks, 256, 0, stream>>>(rp, csrc, cw, Hbuf, h1, 1.0f);
        gemm_mfma<<<gemm_grid, 256, 0, stream>>>(h1, N_NODES, HID, HID,
                                                 WtHh + (size_t)l1 * 384 * HID,
                                                 WtHl + (size_t)l1 * 384 * HID,
                                                 B1, xcat, Hbuf, xcat);
        spmm_kernel<<<spmm_blocks, 256, 0, stream>>>(rp, csrc, cw, Hbuf, xcat, 0.5f);
    }

    // --- output layer ---
    out_gemm<<<(N_NODES + 3) / 4, 256, 0, stream>>>(xcat, w_out, l_out, b_out, H3, T3);
    out_spmm<<<(N_NODES + 255) / 256, 256, 0, stream>>>(rp, csrc, cw, H3, T3, xout);
}